// Round 11
// baseline (961.387 us; speedup 1.0000x reference)
//
#include <hip/hip_runtime.h>

typedef _Float16 half2v __attribute__((ext_vector_type(2)));
typedef __fp16 pk2 __attribute__((ext_vector_type(2)));

#define T_LEN 1024
#define NBATCH 1024
#define HID 20
#define G_B 2      // batch elements per wave (lane groups of 20)
#define STEPS 4    // timesteps per superstep (one barrier per STEPS steps)

#if defined(__has_builtin)
#if __has_builtin(__builtin_amdgcn_fdot2)
#define HAVE_FDOT2 1
#endif
#if __has_builtin(__builtin_amdgcn_cvt_pkrtz)
#define HAVE_PKRTZ 1
#endif
#endif

__device__ __forceinline__ float fdot2_(half2v a, half2v b, float c) {
#ifdef HAVE_FDOT2
    return __builtin_amdgcn_fdot2(a, b, c, false);
#else
    return c + (float)a[0] * (float)b[0] + (float)a[1] * (float)b[1];
#endif
}

__device__ __forceinline__ half2v pack2(float a, float b) {
    half2v r; r[0] = (_Float16)a; r[1] = (_Float16)b; return r;
}

__device__ __forceinline__ half2v pack_rtz(float a, float b) {
#ifdef HAVE_PKRTZ
    pk2 p = __builtin_amdgcn_cvt_pkrtz(a, b);
    return __builtin_bit_cast(half2v, p);
#else
    return pack2(a, b);
#endif
}

__device__ __forceinline__ float sigm(float z) {
    return 1.0f / (1.0f + __expf(-z));
}
__device__ __forceinline__ float tanh_s(float z) {
    return 2.0f / (1.0f + __expf(-2.0f * z)) - 1.0f;
}

// Load 20 f16 (one 24-half / 48B row, 16B-aligned) into 10 half2.
__device__ __forceinline__ void load_h20(const _Float16* row, half2v hp[10]) {
    uint4 q0 = *(const uint4*)(row);
    uint4 q1 = *(const uint4*)(row + 8);
    uint2 q2 = *(const uint2*)(row + 16);
    hp[0] = __builtin_bit_cast(half2v, q0.x);
    hp[1] = __builtin_bit_cast(half2v, q0.y);
    hp[2] = __builtin_bit_cast(half2v, q0.z);
    hp[3] = __builtin_bit_cast(half2v, q0.w);
    hp[4] = __builtin_bit_cast(half2v, q1.x);
    hp[5] = __builtin_bit_cast(half2v, q1.y);
    hp[6] = __builtin_bit_cast(half2v, q1.z);
    hp[7] = __builtin_bit_cast(half2v, q1.w);
    hp[8] = __builtin_bit_cast(half2v, q2.x);
    hp[9] = __builtin_bit_cast(half2v, q2.y);
}

// 20-element dot, two independent depth-5 chains.
__device__ __forceinline__ float dot20s(const half2v W[10], const half2v h[10]) {
    float a0 = 0.f, a1 = 0.f;
#pragma unroll
    for (int k = 0; k < 5; ++k) {
        a0 = fdot2_(W[k],     h[k],     a0);
        a1 = fdot2_(W[k + 5], h[k + 5], a1);
    }
    return a0 + a1;
}

// Rebuild the packed own-h fragment in-register: 20 shfls + 10 RTZ packs.
// Lane gb+j owns h[j]; result identical on all lanes of the group.
__device__ __forceinline__ void distribute(float hn, int gb, half2v hd[10]) {
#pragma unroll
    for (int k = 0; k < 10; ++k) {
        float e = __shfl(hn, gb + 2 * k, 64);
        float o = __shfl(hn, gb + 2 * k + 1, 64);
        hd[k] = pack_rtz(e, o);
    }
}

// Layer-pipelined 3-wave block, 2 batches/wave, 4 gates/lane, 4 steps/barrier.
// vs Round 10: own-h is rebuilt via shfl (in-register) instead of LDS
// write->readback; the ds_write to the ring is fire-and-forget (consumed by
// the wave above only after the barrier). Below-dots for step i+1 are
// computed inside step i to fill the exp/shfl latency bubbles.
__global__ void __launch_bounds__(192, 2) lstm3_shfl(
    const float* __restrict__ x,
    const float* __restrict__ wih0, const float* __restrict__ whh0,
    const float* __restrict__ bih0, const float* __restrict__ bhh0,
    const float* __restrict__ wih1, const float* __restrict__ whh1,
    const float* __restrict__ bih1, const float* __restrict__ bhh1,
    const float* __restrict__ wih2, const float* __restrict__ whh2,
    const float* __restrict__ bih2, const float* __restrict__ bhh2,
    const float* __restrict__ fcw, const float* __restrict__ fcb,
    float* __restrict__ out)
{
    __shared__ __align__(16) float xlds[G_B * T_LEN];        // interleaved [t][g]
    __shared__ __align__(16) _Float16 rings[3][8][G_B * 24]; // depth-8 rings

    const int tid = threadIdx.x;
    const int wv = tid / 64;
    const int lane = tid & 63;
    const long b_base = (long)blockIdx.x * G_B;

    {
        // stage x interleaved: xlds[2*t + g] = x[b_base+g][t]
        const float* xg = x + b_base * T_LEN;
        for (int i = tid; i < G_B * T_LEN; i += 192) {
            const int t = i & (T_LEN - 1);
            const int g = i >> 10;
            xlds[2 * t + g] = xg[i];
        }
        for (int i = tid; i < 3 * 8 * G_B * 24; i += 192)
            ((_Float16*)rings)[i] = (_Float16)0.0f;
    }

    const bool act = lane < G_B * HID;
    const int g = act ? (lane / HID) : 0;
    const int j = act ? (lane % HID) : 0;
    const int gb = g * HID;

    const float* whh = (wv == 0) ? whh0 : (wv == 1) ? whh1 : whh2;
    const float* wih = (wv == 0) ? wih0 : (wv == 1) ? wih1 : wih2;
    const float* bih = (wv == 0) ? bih0 : (wv == 1) ? bih1 : bih2;
    const float* bhh = (wv == 0) ? bhh0 : (wv == 1) ? bhh1 : bhh2;

    // All 4 gate rows (i,f,g,o) of unit j in VGPRs.
    half2v Whh[4][10];
    half2v Wih[4][10];   // waves 1,2
    float bias[4];
    float wx[4] = {0.f, 0.f, 0.f, 0.f};
#pragma unroll
    for (int gt = 0; gt < 4; ++gt) {
        const int r = gt * HID + j;
#pragma unroll
        for (int k4 = 0; k4 < 5; ++k4) {
            float4 v = *(const float4*)(whh + r * HID + 4 * k4);
            Whh[gt][2 * k4]     = pack2(v.x, v.y);
            Whh[gt][2 * k4 + 1] = pack2(v.z, v.w);
        }
        bias[gt] = bih[r] + bhh[r];
        if (wv == 0) {
            wx[gt] = wih[r];  // w_ih0 is (80,1)
        } else {
#pragma unroll
            for (int k4 = 0; k4 < 5; ++k4) {
                float4 v = *(const float4*)(wih + r * HID + 4 * k4);
                Wih[gt][2 * k4]     = pack2(v.x, v.y);
                Wih[gt][2 * k4 + 1] = pack2(v.z, v.w);
            }
        }
    }

    _Float16* const own_base = &rings[wv][0][0];
    const _Float16* const bel_base = (wv > 0) ? &rings[wv - 1][0][0]
                                              : &rings[0][0][0];

    float c = 0.0f;                              // cell state (own unit)
    float oA[4] = {0.f, 0.f, 0.f, 0.f};          // own-h partials (h(-1)=0)

    __syncthreads();

    const int SS = T_LEN / STEPS;  // supersteps per wave
    const int ROW = G_B * 24;      // halfs per timestep slot

    for (int s = 0; s < SS + 2; ++s) {
        const int m = s - wv;
        if (m >= 0 && m < SS) {
            const int qb = (m & 1) * (STEPS * ROW) + g * 24;  // quad base
            const int t0 = STEPS * m;

            // hoist the 4 below-rows (one lgkm wait, amortized over 4 steps)
            half2v hb[STEPS][10];
            if (wv > 0) {
#pragma unroll
                for (int i = 0; i < STEPS; ++i)
                    load_h20(bel_base + qb + i * ROW, hb[i]);
            }

            // pre-gates for step 0
            float pre[4];
            if (wv == 0) {
                const float x0 = xlds[2 * t0 + g];
#pragma unroll
                for (int gt = 0; gt < 4; ++gt)
                    pre[gt] = bias[gt] + oA[gt] + wx[gt] * x0;
            } else {
#pragma unroll
                for (int gt = 0; gt < 4; ++gt)
                    pre[gt] = bias[gt] + oA[gt] + dot20s(Wih[gt], hb[0]);
            }

#pragma unroll
            for (int i = 0; i < STEPS; ++i) {
                // activations (4 parallel exp chains)
                float si = sigm(pre[0]);
                float sf = sigm(pre[1]);
                float tg = tanh_s(pre[2]);
                float so = sigm(pre[3]);

                // below-part of NEXT step's pre-gates: independent work that
                // fills the exp/shfl latency bubbles of THIS step.
                float nb[4];
                if (i < STEPS - 1) {
                    if (wv == 0) {
                        const float xn = xlds[2 * (t0 + i + 1) + g];
#pragma unroll
                        for (int gt = 0; gt < 4; ++gt)
                            nb[gt] = bias[gt] + wx[gt] * xn;
                    } else {
#pragma unroll
                        for (int gt = 0; gt < 4; ++gt)
                            nb[gt] = bias[gt] + dot20s(Wih[gt], hb[i + 1]);
                    }
                }

                c = sf * c + si * tg;
                const float hn = so * tanh_s(c);

                // in-register distribute (RTZ); write the SAME RTZ value to
                // the ring (fire-and-forget; consumed only after the barrier)
                half2v hd[10];
                distribute(hn, gb, hd);
                if (act) {
                    pk2 p = __builtin_amdgcn_cvt_pkrtz(hn, hn);
                    (own_base + qb + i * ROW)[j] =
                        __builtin_bit_cast(_Float16, (short)__builtin_bit_cast(int, p));
                }

                // own-h dots -> next pre-gates (no LDS readback)
                if (i < STEPS - 1) {
#pragma unroll
                    for (int gt = 0; gt < 4; ++gt)
                        pre[gt] = nb[gt] + dot20s(Whh[gt], hd);
                } else {
#pragma unroll
                    for (int gt = 0; gt < 4; ++gt)
                        oA[gt] = dot20s(Whh[gt], hd);
                }
            }
        }
        __syncthreads();  // publish this superstep's 4 rows to the wave above
    }

    // FC epilogue: h2(T-1), slot (T_LEN-1)&7 = 7
    if (wv == 2 && lane < 2 * G_B) {
        const int gg = lane >> 1, o = lane & 1;
        float acc = fcb[o];
        const _Float16* h2 = &rings[2][7][gg * 24];
#pragma unroll
        for (int k = 0; k < HID; ++k) {
            acc += fcw[o * HID + k] * (float)h2[k];
        }
        out[(b_base + gg) * 2 + o] = acc;
    }
}

extern "C" void kernel_launch(void* const* d_in, const int* in_sizes, int n_in,
                              void* d_out, int out_size, void* d_ws, size_t ws_size,
                              hipStream_t stream) {
    const float* x    = (const float*)d_in[0];
    const float* wih0 = (const float*)d_in[1];
    const float* whh0 = (const float*)d_in[2];
    const float* bih0 = (const float*)d_in[3];
    const float* bhh0 = (const float*)d_in[4];
    const float* wih1 = (const float*)d_in[5];
    const float* whh1 = (const float*)d_in[6];
    const float* bih1 = (const float*)d_in[7];
    const float* bhh1 = (const float*)d_in[8];
    const float* wih2 = (const float*)d_in[9];
    const float* whh2 = (const float*)d_in[10];
    const float* bih2 = (const float*)d_in[11];
    const float* bhh2 = (const float*)d_in[12];
    const float* fcw  = (const float*)d_in[13];
    const float* fcb  = (const float*)d_in[14];

    lstm3_shfl<<<dim3(NBATCH / G_B), dim3(192), 0, stream>>>(
        x, wih0, whh0, bih0, bhh0,
        wih1, whh1, bih1, bhh1,
        wih2, whh2, bih2, bhh2,
        fcw, fcb, (float*)d_out);
}